// Round 11
// baseline (514.992 us; speedup 1.0000x reference)
//
#include <hip/hip_runtime.h>
#include <math.h>

#define N_ 64
#define C_ 256
#define T_ 64
#define V_ 25
#define H_ 3
#define O_ 256
#define D_ 32
#define HD_ 96

using short8 = __attribute__((ext_vector_type(8))) short;
using f32x4  = __attribute__((ext_vector_type(4))) float;

// d_ws layout in ushort (bf16) units, weights pre-swizzled to MFMA A-fragment order:
// tile = (row-tile ot, K-step ks); within tile: lane*8 + j, where
//   row = ot*16 + (lane&15), c = ks*32 + (lane>>4)*8 + j
#define WS_WD   0          // 3 heads * 16 ot * 8 ks * 512 = 196608
#define WS_WG   196608     // 16*8*512 = 65536
#define WS_WPHI 262144     // 6*8*512  = 24576
#define WS_WPSI 286720     // 6*8*512  = 24576   (total 311296 ushort = 622592 B)

__device__ __forceinline__ unsigned short f2bf(float f) {
    unsigned int u = __float_as_uint(f);
    unsigned int r = (u + 0x7fffu + ((u >> 16) & 1u)) >> 16;
    return (unsigned short)r;
}

__global__ __launch_bounds__(256)
void prep_weights(const float* __restrict__ Wd, const float* __restrict__ Wg,
                  const float* __restrict__ Wphi, const float* __restrict__ Wpsi,
                  unsigned short* __restrict__ ws) {
    int gid = blockIdx.x * 256 + threadIdx.x;
    if (gid >= 608 * 64) return;
    int tile = gid >> 6, lane = gid & 63;
    int lcol = lane & 15, lrow = lane >> 4;
    const float* W;
    unsigned short* base;
    int ot, ks;
    if (tile < 384) {                       // W_d: [h][o][c]
        int h = tile >> 7, r = tile & 127;
        ot = r >> 3; ks = r & 7;
        W = Wd + (size_t)h * O_ * C_;
        base = ws + WS_WD + (size_t)tile * 512;
    } else if (tile < 512) {                // W_g: [o][c]
        int r = tile - 384;
        ot = r >> 3; ks = r & 7;
        W = Wg;
        base = ws + WS_WG + (size_t)r * 512;
    } else if (tile < 560) {                // W_phi: [e][c]
        int r = tile - 512;
        ot = r >> 3; ks = r & 7;
        W = Wphi;
        base = ws + WS_WPHI + (size_t)r * 512;
    } else {                                // W_psi
        int r = tile - 560;
        ot = r >> 3; ks = r & 7;
        W = Wpsi;
        base = ws + WS_WPSI + (size_t)r * 512;
    }
    int row = ot * 16 + lcol;
    int c0  = ks * 32 + lrow * 8;
    const float* s = W + (size_t)row * C_ + c0;
    unsigned int p[4];
    #pragma unroll
    for (int q = 0; q < 4; ++q) {
        unsigned short lo = f2bf(s[2 * q]);
        unsigned short hi = f2bf(s[2 * q + 1]);
        p[q] = (unsigned int)lo | ((unsigned int)hi << 16);
    }
    uint4 pk = make_uint4(p[0], p[1], p[2], p[3]);
    *(uint4*)(base + (size_t)lane * 8) = pk;
}

// LDS map (bytes):
//   xbT  [32][256] bf16, XOR ^((v&7)<<4)         @ 0      (16384)
//   Afin [3][32][32] bf16, XOR ^((v&7)<<4)       @ 16384  (6144)
//   scratch @ 22528:
//     phiB [32][104] bf16 ([v][e], 16B rows)     @ 22528  (6656)
//     psiB [32][104] bf16                        @ 29184  (6656)
//     S    [75][28]  f32                         @ 35840  (8400)
//     Mlds [256][40] bf16 (aliases phiB..S)      @ 22528  (20480)
#define L_AFIN 16384
#define L_SCR  22528
#define L_PHIB L_SCR
#define L_PSIB (L_SCR + 6656)
#define L_S    (L_SCR + 13312)
#define L_M    L_SCR
#define L_TOT  44240

__global__ __launch_bounds__(256)
void hdgc_mfma(const float* __restrict__ x,
               const float* __restrict__ A_prior,
               const float* __restrict__ A_2hop,
               const float* __restrict__ beta_p,
               const float* __restrict__ lam_p,
               const float* __restrict__ b_phi,
               const float* __restrict__ b_psi,
               const unsigned short* __restrict__ ws,
               const float* __restrict__ b_d,
               const float* __restrict__ bn_gamma,
               const float* __restrict__ bn_beta,
               const float* __restrict__ bn_mean,
               const float* __restrict__ bn_var,
               const float* __restrict__ b_g,
               float* __restrict__ out) {
    __shared__ __align__(16) char lds[L_TOT];
    char*           xbT  = lds;
    char*           Afin = lds + L_AFIN;
    unsigned short* phiB = (unsigned short*)(lds + L_PHIB);
    unsigned short* psiB = (unsigned short*)(lds + L_PSIB);
    float*          Slds = (float*)(lds + L_S);
    char*           Mlds = lds + L_M;

    const int tid  = threadIdx.x;
    const int lane = tid & 63, wid = tid >> 6;
    const int lcol = lane & 15, lrow = lane >> 4;
    const int b = blockIdx.x, n = b / T_, t = b - n * T_;
    const size_t xbase = (size_t)n * (C_ * T_ * V_) + (size_t)t * V_;

    // ---- stage: zero xbT pad rows + Afin, load x slice as bf16 (swizzled [v][c]) ----
    for (int i = tid; i < 7 * 256; i += 256) {          // rows v=25..31 -> 0
        int v = 25 + (i >> 8), c = i & 255;
        *(unsigned short*)(xbT + (((v << 9) + (c << 1)) ^ ((v & 7) << 4))) = 0;
    }
    for (int i = tid; i < 3 * 32 * 32; i += 256)
        ((unsigned short*)Afin)[i] = 0;
    for (int i = tid; i < 128 * V_; i += 256) {         // c-pairs: pack 2 bf16 -> b32
        int p = i / V_, v = i - p * V_;
        int c = p * 2;
        const float* xs = x + xbase + (size_t)c * (T_ * V_) + v;
        unsigned int lo = f2bf(xs[0]);
        unsigned int hi = f2bf(xs[T_ * V_]);
        *(unsigned int*)(xbT + (((v << 9) + (c << 1)) ^ ((v & 7) << 4))) = lo | (hi << 16);
    }
    __syncthreads();

    // ---- phi/psi: MFMA, D -> bf16 [v][e] (stride 104, +bias) ----
    {
        const unsigned short* wsrc = ws + ((wid >> 1) ? WS_WPSI : WS_WPHI);
        const float* bias = (wid >> 1) ? b_psi : b_phi;
        unsigned short* dstB = (wid >> 1) ? psiB : phiB;
        int otbase = (wid & 1) * 3;
        f32x4 acc[3][2];
        #pragma unroll
        for (int oi = 0; oi < 3; ++oi)
            #pragma unroll
            for (int wt = 0; wt < 2; ++wt) acc[oi][wt] = (f32x4){0.f, 0.f, 0.f, 0.f};
        for (int ks = 0; ks < 8; ++ks) {
            const int cb = (ks * 32 + lrow * 8) << 1;
            short8 b0 = *(const short8*)(xbT + (((lcol << 9) + cb) ^ ((lcol & 7) << 4)));
            const int v1 = 16 + lcol;
            short8 b1 = *(const short8*)(xbT + (((v1 << 9) + cb) ^ ((v1 & 7) << 4)));
            #pragma unroll
            for (int oi = 0; oi < 3; ++oi) {
                int ot = otbase + oi;
                short8 a = *(const short8*)(wsrc + (((ot << 3) + ks) << 9) + lane * 8);
                acc[oi][0] = __builtin_amdgcn_mfma_f32_16x16x32_bf16(a, b0, acc[oi][0], 0, 0, 0);
                acc[oi][1] = __builtin_amdgcn_mfma_f32_16x16x32_bf16(a, b1, acc[oi][1], 0, 0, 0);
            }
        }
        #pragma unroll
        for (int oi = 0; oi < 3; ++oi) {
            int ot = otbase + oi;
            #pragma unroll
            for (int r = 0; r < 4; ++r) {
                int e = ot * 16 + lrow * 4 + r;
                float bv = bias[e];
                if (lcol < 25) dstB[lcol * 104 + e]        = f2bf(acc[oi][0][r] + bv);
                if (lcol < 9)  dstB[(16 + lcol) * 104 + e] = f2bf(acc[oi][1][r] + bv);
            }
        }
    }
    __syncthreads();

    // ---- scores: MFMA S_h = phi_h @ psi_h^T (waves 0..2, one head each) ----
    if (wid < H_) {
        const int h = wid;
        const int eo = h * 32 + lrow * 8;
        short8 a0 = *(const short8*)(phiB + lcol * 104 + eo);
        short8 a1 = *(const short8*)(phiB + (16 + lcol) * 104 + eo);
        short8 q0 = *(const short8*)(psiB + lcol * 104 + eo);
        short8 q1 = *(const short8*)(psiB + (16 + lcol) * 104 + eo);
        f32x4 s00 = (f32x4){0.f, 0.f, 0.f, 0.f}, s01 = s00, s10 = s00, s11 = s00;
        s00 = __builtin_amdgcn_mfma_f32_16x16x32_bf16(a0, q0, s00, 0, 0, 0);
        s01 = __builtin_amdgcn_mfma_f32_16x16x32_bf16(a0, q1, s01, 0, 0, 0);
        s10 = __builtin_amdgcn_mfma_f32_16x16x32_bf16(a1, q0, s10, 0, 0, 0);
        s11 = __builtin_amdgcn_mfma_f32_16x16x32_bf16(a1, q1, s11, 0, 0, 0);
        const float scf = 0.17677669529663687f;  // 32^-0.5
        #pragma unroll
        for (int r = 0; r < 4; ++r) {
            int v0 = lrow * 4 + r, v1 = 16 + v0;
            if (v0 < 25) {
                float* row = Slds + (h * 25 + v0) * 28;
                row[lcol] = s00[r] * scf;
                if (16 + lcol < 25) row[16 + lcol] = s01[r] * scf;
            }
            if (v1 < 25) {
                float* row = Slds + (h * 25 + v1) * 28;
                row[lcol] = s10[r] * scf;
                if (16 + lcol < 25) row[16 + lcol] = s11[r] * scf;
            }
        }
    }
    __syncthreads();

    // ---- softmax + combine priors -> Afin bf16 (swizzled [h*32+v][w]) ----
    if (tid < H_ * V_) {
        int h = tid / 25, v = tid - h * 25;
        float lam  = fminf(fmaxf(lam_p[0], 0.f), 1.f);
        float beta = beta_p[0];
        const float* row = Slds + tid * 28;
        float mx = -1e30f;
        #pragma unroll
        for (int w = 0; w < 25; ++w) mx = fmaxf(mx, row[w]);
        float e[25], sum = 0.f;
        #pragma unroll
        for (int w = 0; w < 25; ++w) { e[w] = __expf(row[w] - mx); sum += e[w]; }
        float sc = lam / sum;
        const float* Ap = A_prior + tid * 25;
        const float* A2 = A_2hop + tid * 25;
        #pragma unroll
        for (int w = 0; w < 25; ++w) {
            float af = Ap[w] + beta * A2[w] + sc * e[w];
            *(unsigned short*)(Afin + (((((h * 32 + v) << 6) + (w << 1))) ^ ((v & 7) << 4))) = f2bf(af);
        }
    }
    __syncthreads();

    // ---- per-head: M = W_d[h] @ xb (MFMA) -> Mlds bf16 ; PV: out += M @ Afin[h]^T ----
    f32x4 oacc[4][2], gacc[4][2];
    #pragma unroll
    for (int oi = 0; oi < 4; ++oi)
        #pragma unroll
        for (int vt = 0; vt < 2; ++vt) {
            oacc[oi][vt] = (f32x4){0.f, 0.f, 0.f, 0.f};
            gacc[oi][vt] = (f32x4){0.f, 0.f, 0.f, 0.f};
        }

    for (int h = 0; h < H_; ++h) {
        f32x4 macc[4][2];
        #pragma unroll
        for (int oi = 0; oi < 4; ++oi)
            #pragma unroll
            for (int wt = 0; wt < 2; ++wt) macc[oi][wt] = (f32x4){0.f, 0.f, 0.f, 0.f};
        for (int ks = 0; ks < 8; ++ks) {
            const int cb = (ks * 32 + lrow * 8) << 1;
            short8 b0 = *(const short8*)(xbT + (((lcol << 9) + cb) ^ ((lcol & 7) << 4)));
            const int v1 = 16 + lcol;
            short8 b1 = *(const short8*)(xbT + (((v1 << 9) + cb) ^ ((v1 & 7) << 4)));
            #pragma unroll
            for (int oi = 0; oi < 4; ++oi) {
                int ot = wid * 4 + oi;
                short8 a = *(const short8*)(ws + WS_WD + ((((h * 16 + ot) << 3) + ks) << 9) + lane * 8);
                macc[oi][0] = __builtin_amdgcn_mfma_f32_16x16x32_bf16(a, b0, macc[oi][0], 0, 0, 0);
                macc[oi][1] = __builtin_amdgcn_mfma_f32_16x16x32_bf16(a, b1, macc[oi][1], 0, 0, 0);
            }
        }
        #pragma unroll
        for (int oi = 0; oi < 4; ++oi) {
            int ot = wid * 4 + oi;
            #pragma unroll
            for (int r = 0; r < 4; ++r) {
                int o = ot * 16 + lrow * 4 + r;
                *(unsigned short*)(Mlds + o * 80 + (lcol << 1))        = f2bf(macc[oi][0][r]);
                *(unsigned short*)(Mlds + o * 80 + ((16 + lcol) << 1)) = f2bf(macc[oi][1][r]);
            }
        }
        __syncthreads();
        // PV: A-frag from Mlds (row o=lane&15, k=w), B-frag from Afin (col v=lane&15, k=w)
        {
            short8 af[4];
            #pragma unroll
            for (int oi = 0; oi < 4; ++oi) {
                int ot = wid * 4 + oi;
                af[oi] = *(const short8*)(Mlds + (ot * 16 + lcol) * 80 + (lrow << 4));
            }
            #pragma unroll
            for (int vt = 0; vt < 2; ++vt) {
                int v = vt * 16 + lcol;
                short8 bf = *(const short8*)(Afin + ((((h * 32 + v) << 6) + (lrow << 4)) ^ ((v & 7) << 4)));
                #pragma unroll
                for (int oi = 0; oi < 4; ++oi)
                    oacc[oi][vt] = __builtin_amdgcn_mfma_f32_16x16x32_bf16(af[oi], bf, oacc[oi][vt], 0, 0, 0);
            }
        }
        __syncthreads();
    }

    // ---- gate GEMM (kept in regs; D-layout matches oacc) ----
    for (int ks = 0; ks < 8; ++ks) {
        const int cb = (ks * 32 + lrow * 8) << 1;
        short8 b0 = *(const short8*)(xbT + (((lcol << 9) + cb) ^ ((lcol & 7) << 4)));
        const int v1 = 16 + lcol;
        short8 b1 = *(const short8*)(xbT + (((v1 << 9) + cb) ^ ((v1 & 7) << 4)));
        #pragma unroll
        for (int oi = 0; oi < 4; ++oi) {
            int ot = wid * 4 + oi;
            short8 a = *(const short8*)(ws + WS_WG + (((ot << 3) + ks) << 9) + lane * 8);
            gacc[oi][0] = __builtin_amdgcn_mfma_f32_16x16x32_bf16(a, b0, gacc[oi][0], 0, 0, 0);
            gacc[oi][1] = __builtin_amdgcn_mfma_f32_16x16x32_bf16(a, b1, gacc[oi][1], 0, 0, 0);
        }
    }

    // ---- epilogue: +b_d, BN, sigmoid gate, residual (bf16 x), relu, store ----
    #pragma unroll
    for (int oi = 0; oi < 4; ++oi) {
        int ot = wid * 4 + oi;
        #pragma unroll
        for (int r = 0; r < 4; ++r) {
            int o = ot * 16 + lrow * 4 + r;
            float bdsum = b_d[o] + b_d[O_ + o] + b_d[2 * O_ + o];
            float inv  = rsqrtf(bn_var[o] + 1e-5f) * bn_gamma[o];
            float mean = bn_mean[o], bnb = bn_beta[o], bg = b_g[o];
            float* op = out + xbase + (size_t)o * (T_ * V_);
            #pragma unroll
            for (int vt = 0; vt < 2; ++vt) {
                int v = vt * 16 + lcol;
                if (v < V_) {
                    float pre = (oacc[oi][vt][r] + bdsum - mean) * inv + bnb;
                    float gl  = gacc[oi][vt][r] + bg;
                    float g   = 1.f / (1.f + __expf(-gl));
                    unsigned short xb =
                        *(unsigned short*)(xbT + (((v << 9) + (o << 1)) ^ ((v & 7) << 4)));
                    float res = __uint_as_float(((unsigned int)xb) << 16);
                    float rr = g * pre + res;
                    op[v] = fmaxf(rr, 0.f);
                }
            }
        }
    }
}

extern "C" void kernel_launch(void* const* d_in, const int* in_sizes, int n_in,
                              void* d_out, int out_size, void* d_ws, size_t ws_size,
                              hipStream_t stream) {
    const float* x        = (const float*)d_in[0];
    const float* A_prior  = (const float*)d_in[1];
    const float* A_2hop   = (const float*)d_in[2];
    const float* beta_p   = (const float*)d_in[3];
    const float* lam_p    = (const float*)d_in[4];
    const float* W_phi    = (const float*)d_in[5];
    const float* b_phi    = (const float*)d_in[6];
    const float* W_psi    = (const float*)d_in[7];
    const float* b_psi    = (const float*)d_in[8];
    const float* W_d      = (const float*)d_in[9];
    const float* b_d      = (const float*)d_in[10];
    const float* bn_gamma = (const float*)d_in[11];
    const float* bn_beta  = (const float*)d_in[12];
    const float* bn_mean  = (const float*)d_in[13];
    const float* bn_var   = (const float*)d_in[14];
    const float* W_g      = (const float*)d_in[15];
    const float* b_g      = (const float*)d_in[16];
    unsigned short* ws = (unsigned short*)d_ws;
    float* out = (float*)d_out;

    hipLaunchKernelGGL(prep_weights, dim3(152), dim3(256), 0, stream,
                       W_d, W_g, W_phi, W_psi, ws);
    hipLaunchKernelGGL(hdgc_mfma, dim3(N_ * T_), dim3(256), 0, stream,
                       x, A_prior, A_2hop, beta_p, lam_p,
                       b_phi, b_psi, ws,
                       b_d, bn_gamma, bn_beta, bn_mean, bn_var, b_g, out);
}